// Round 1
// baseline (129.339 us; speedup 1.0000x reference)
//
#include <hip/hip_runtime.h>
#include <math.h>

// Problem constants (from reference setup_inputs): predict_pc 4x3x4096, gt_pc 4x3x4096, fp32.
#define BATCH 4
#define NPTS 4096            // M == N == 4096
#define THREADS 256
#define CHUNKS (NPTS / THREADS)            // 16 chunks of 256 points per batch
#define BLOCKS_PER_DIR (BATCH * CHUNKS)    // 64
#define TOTAL_BLOCKS (2 * BLOCKS_PER_DIR)  // 128

#define EPS 1e-8f
#define BIG 1e30f

// Each block: one direction, one batch, one 256-point chunk.
// Stages the entire candidate cloud (3*4096 floats = 48KB) into LDS,
// each thread scans all 4096 candidates for its point.
__global__ __launch_bounds__(THREADS) void chamfer_min_kernel(
    const float* __restrict__ pred, const float* __restrict__ gt,
    float* __restrict__ partial)
{
    __shared__ float l[3 * NPTS];  // [x(4096) | y(4096) | z(4096)]

    const int bid   = blockIdx.x;
    const int dir   = bid / BLOCKS_PER_DIR;   // 0: points=pred, cand=gt ; 1: swapped
    const int rem   = bid % BLOCKS_PER_DIR;
    const int batch = rem / CHUNKS;
    const int chunk = rem % CHUNKS;

    const float* pts  = (dir == 0) ? pred : gt;
    const float* cand = (dir == 0) ? gt   : pred;

    // Cooperative float4 staging: layout in memory is already [x-row, y-row, z-row].
    {
        const float4* src = (const float4*)(cand + (size_t)batch * 3 * NPTS);
        float4* dst = (float4*)l;
        #pragma unroll
        for (int k = 0; k < (3 * NPTS / 4) / THREADS; ++k)   // 12 iters
            dst[k * THREADS + threadIdx.x] = src[k * THREADS + threadIdx.x];
    }
    __syncthreads();

    // This thread's point (coalesced loads: x,y,z rows are contiguous in m).
    const int i = chunk * THREADS + threadIdx.x;
    const float* pb = pts + (size_t)batch * 3 * NPTS;
    const float px = pb[i];
    const float py = pb[NPTS + i];
    const float pz = pb[2 * NPTS + i];

    // Scan candidates; float4 LDS reads (broadcast — all lanes same address),
    // 4 independent min accumulators to break the v_min dependence chain.
    const float4* lx4 = (const float4*)(l);
    const float4* ly4 = (const float4*)(l + NPTS);
    const float4* lz4 = (const float4*)(l + 2 * NPTS);

    float b0 = BIG, b1 = BIG, b2 = BIG, b3 = BIG;
    #pragma unroll 4
    for (int n4 = 0; n4 < NPTS / 4; ++n4) {
        const float4 gx = lx4[n4];
        const float4 gy = ly4[n4];
        const float4 gz = lz4[n4];
        float dx, dy, dz, d;
        dx = px - gx.x; dy = py - gy.x; dz = pz - gz.x;
        d = dx * dx + dy * dy + dz * dz; b0 = fminf(b0, d);
        dx = px - gx.y; dy = py - gy.y; dz = pz - gz.y;
        d = dx * dx + dy * dy + dz * dz; b1 = fminf(b1, d);
        dx = px - gx.z; dy = py - gy.z; dz = pz - gz.z;
        d = dx * dx + dy * dy + dz * dz; b2 = fminf(b2, d);
        dx = px - gx.w; dy = py - gy.w; dz = pz - gz.w;
        d = dx * dx + dy * dy + dz * dz; b3 = fminf(b3, d);
    }
    float r = sqrtf(fminf(fminf(b0, b1), fminf(b2, b3)) + EPS);

    // Block-sum: wave64 shuffle reduce, then LDS combine of the 4 wave sums.
    #pragma unroll
    for (int off = 32; off; off >>= 1) r += __shfl_down(r, off, 64);
    __shared__ float wsum[THREADS / 64];
    if ((threadIdx.x & 63) == 0) wsum[threadIdx.x >> 6] = r;
    __syncthreads();
    if (threadIdx.x == 0)
        partial[bid] = (wsum[0] + wsum[1]) + (wsum[2] + wsum[3]);
}

// 1 block, 128 threads: reduce 128 block partials, divide by the shared
// mean denominator (B*M == B*N == 16384), write the scalar.
__global__ void chamfer_finalize_kernel(const float* __restrict__ partial,
                                        float* __restrict__ out)
{
    float v = partial[threadIdx.x];
    #pragma unroll
    for (int off = 32; off; off >>= 1) v += __shfl_down(v, off, 64);
    __shared__ float s[2];
    if ((threadIdx.x & 63) == 0) s[threadIdx.x >> 6] = v;
    __syncthreads();
    if (threadIdx.x == 0)
        out[0] = (s[0] + s[1]) * (1.0f / (float)(BATCH * NPTS));
}

extern "C" void kernel_launch(void* const* d_in, const int* in_sizes, int n_in,
                              void* d_out, int out_size, void* d_ws, size_t ws_size,
                              hipStream_t stream) {
    const float* pred = (const float*)d_in[0];  // 4x3x4096
    const float* gt   = (const float*)d_in[1];  // 4x3x4096
    float* out     = (float*)d_out;             // scalar
    float* partial = (float*)d_ws;              // 128 floats, every slot overwritten

    chamfer_min_kernel<<<TOTAL_BLOCKS, THREADS, 0, stream>>>(pred, gt, partial);
    chamfer_finalize_kernel<<<1, 128, 0, stream>>>(partial, out);
}

// Round 2
// 77.405 us; speedup vs baseline: 1.6710x; 1.6710x over previous
//
#include <hip/hip_runtime.h>
#include <math.h>

// Problem: predict_pc 4x3x4096, gt_pc 4x3x4096 fp32; symmetric 1-NN chamfer mean.
#define BATCH 4
#define NPTS 4096
#define THREADS 256
#define P 4                    // points per thread (amortizes LDS reads: VALU-bound at P>=3)
#define SEGS 16                // candidate segments (parallelism knob)
#define CSEG (NPTS / SEGS)     // 256 candidates per segment
#define PTGRPS (NPTS / (THREADS * P))          // 4 point-groups per (dir,batch)
#define PASS1_BLOCKS (2 * BATCH * PTGRPS * SEGS)  // 512
#define TOTAL_PTS (2 * BATCH * NPTS)           // 32768 (fwd + bwd point slots)
#define PASS2_BLOCKS 32

#define EPS 1e-8f
#define BIG 1e30f

// ws layout: [0 .. SEGS*TOTAL_PTS) partial mins (2MB) ; then PASS2_BLOCKS block sums.
#define PMIN_FLOATS (SEGS * TOTAL_PTS)

// Pass 1: each block = (dir, batch, point-group of 1024 pts, candidate-segment of 256).
// Stages 256 candidates (3KB) in LDS; each thread scans them for its 4 points.
__global__ __launch_bounds__(THREADS) void chamfer_pass1(
    const float* __restrict__ pred, const float* __restrict__ gt,
    float* __restrict__ pmin)
{
    __shared__ float lx[CSEG], ly[CSEG], lz[CSEG];

    const int bid   = blockIdx.x;
    const int seg   = bid & (SEGS - 1);
    const int ptgrp = (bid >> 4) & (PTGRPS - 1);
    const int batch = (bid >> 6) & (BATCH - 1);
    const int dir   = bid >> 8;

    const float* pts  = (dir == 0) ? pred : gt;
    const float* cand = (dir == 0) ? gt   : pred;

    // Stage this segment's candidates: 256 cands, 1 scalar per coord per thread (coalesced).
    {
        const float* cb = cand + (size_t)batch * 3 * NPTS + seg * CSEG;
        const int t = threadIdx.x;
        lx[t] = cb[t];
        ly[t] = cb[NPTS + t];
        lz[t] = cb[2 * NPTS + t];
    }
    __syncthreads();

    // This thread's 4 points (coalesced: stride-256 within the 1024-pt group).
    const float* pb = pts + (size_t)batch * 3 * NPTS;
    const int pbase = ptgrp * (THREADS * P) + threadIdx.x;
    float px[P], py[P], pz[P], m[P];
    #pragma unroll
    for (int k = 0; k < P; ++k) {
        const int i = pbase + k * THREADS;
        px[k] = pb[i];
        py[k] = pb[NPTS + i];
        pz[k] = pb[2 * NPTS + i];
        m[k] = BIG;
    }

    const float4* lx4 = (const float4*)lx;
    const float4* ly4 = (const float4*)ly;
    const float4* lz4 = (const float4*)lz;

    // 64 groups of 4 candidates. Per group: 3 ds_read_b128 (broadcast) + 4P*7 VALU.
    #pragma unroll 2
    for (int g = 0; g < CSEG / 4; ++g) {
        const float4 X = lx4[g];
        const float4 Y = ly4[g];
        const float4 Z = lz4[g];
        #pragma unroll
        for (int k = 0; k < P; ++k) {
            float dx, dy, dz, d0, d1, d2, d3;
            dx = px[k] - X.x; dy = py[k] - Y.x; dz = pz[k] - Z.x;
            d0 = fmaf(dx, dx, fmaf(dy, dy, dz * dz));
            dx = px[k] - X.y; dy = py[k] - Y.y; dz = pz[k] - Z.y;
            d1 = fmaf(dx, dx, fmaf(dy, dy, dz * dz));
            dx = px[k] - X.z; dy = py[k] - Y.z; dz = pz[k] - Z.z;
            d2 = fmaf(dx, dx, fmaf(dy, dy, dz * dz));
            dx = px[k] - X.w; dy = py[k] - Y.w; dz = pz[k] - Z.w;
            d3 = fmaf(dx, dx, fmaf(dy, dy, dz * dz));
            m[k] = fminf(m[k], fminf(fminf(d0, d1), fminf(d2, d3)));
        }
    }

    // Store partial mins: pmin[seg][global_point], coalesced per k.
    const int gp = dir * (BATCH * NPTS) + batch * NPTS + pbase;
    #pragma unroll
    for (int k = 0; k < P; ++k)
        pmin[(size_t)seg * TOTAL_PTS + gp + k * THREADS] = m[k];
}

// Pass 2: per point, min over the 16 segment-mins, sqrt(+eps), block-sum.
__global__ __launch_bounds__(THREADS) void chamfer_pass2(
    const float* __restrict__ pmin, float* __restrict__ bsum)
{
    const int pbase = blockIdx.x * (THREADS * P) + threadIdx.x;
    float acc = 0.0f;
    #pragma unroll
    for (int k = 0; k < P; ++k) {
        const int p = pbase + k * THREADS;
        float v = BIG;
        #pragma unroll
        for (int s = 0; s < SEGS; ++s)
            v = fminf(v, pmin[(size_t)s * TOTAL_PTS + p]);
        acc += sqrtf(v + EPS);
    }
    #pragma unroll
    for (int off = 32; off; off >>= 1) acc += __shfl_down(acc, off, 64);
    __shared__ float wsum[THREADS / 64];
    if ((threadIdx.x & 63) == 0) wsum[threadIdx.x >> 6] = acc;
    __syncthreads();
    if (threadIdx.x == 0)
        bsum[blockIdx.x] = (wsum[0] + wsum[1]) + (wsum[2] + wsum[3]);
}

// Pass 3: reduce 32 block sums; both means share denominator B*NPTS = 16384.
__global__ void chamfer_pass3(const float* __restrict__ bsum, float* __restrict__ out)
{
    float v = (threadIdx.x < PASS2_BLOCKS) ? bsum[threadIdx.x] : 0.0f;
    #pragma unroll
    for (int off = 32; off; off >>= 1) v += __shfl_down(v, off, 64);
    if (threadIdx.x == 0)
        out[0] = v * (1.0f / (float)(BATCH * NPTS));
}

extern "C" void kernel_launch(void* const* d_in, const int* in_sizes, int n_in,
                              void* d_out, int out_size, void* d_ws, size_t ws_size,
                              hipStream_t stream) {
    const float* pred = (const float*)d_in[0];
    const float* gt   = (const float*)d_in[1];
    float* out  = (float*)d_out;
    float* pmin = (float*)d_ws;                  // 2MB partial mins (all slots written)
    float* bsum = pmin + PMIN_FLOATS;            // 32 block sums

    chamfer_pass1<<<PASS1_BLOCKS, THREADS, 0, stream>>>(pred, gt, pmin);
    chamfer_pass2<<<PASS2_BLOCKS, THREADS, 0, stream>>>(pmin, bsum);
    chamfer_pass3<<<1, 64, 0, stream>>>(bsum, out);
}

// Round 3
// 71.469 us; speedup vs baseline: 1.8097x; 1.0830x over previous
//
#include <hip/hip_runtime.h>
#include <math.h>

// Problem: predict_pc 4x3x4096, gt_pc 4x3x4096 fp32; symmetric 1-NN chamfer mean.
// Inner-loop math: min d2 = p2+g2-2*p.g  <=>  max score = p.g - g2/2.
// Candidates staged in LDS as float4 (x, y, z, -g2/2) -> 4 VALU per pair.
#define BATCH 4
#define NPTS 4096
#define THREADS 256
#define P 8                          // points per thread (VALU-bound for P>6)
#define SEGS 32                      // candidate segments
#define CSEG (NPTS / SEGS)           // 128 candidates per segment
#define PTGRPS (NPTS / (THREADS * P))        // 2 point-groups per (dir,batch)
#define PASS1_BLOCKS (2 * BATCH * PTGRPS * SEGS)  // 512
#define TOTAL_PTS (2 * BATCH * NPTS)         // 32768
#define PASS2_BLOCKS 32
#define P2 (TOTAL_PTS / (PASS2_BLOCKS * THREADS))  // 4

#define EPS 1e-8f
#define BIG 1e30f

// ws layout: [0 .. SEGS*TOTAL_PTS) partial d2 mins (4MB); then PASS2_BLOCKS sums.
#define PMIN_FLOATS (SEGS * TOTAL_PTS)

__global__ __launch_bounds__(THREADS) void chamfer_pass1(
    const float* __restrict__ pred, const float* __restrict__ gt,
    float* __restrict__ pmin)
{
    __shared__ float4 lc[CSEG];   // (x, y, z, -0.5*g2) per candidate

    const int bid   = blockIdx.x;
    const int seg   = bid & (SEGS - 1);
    const int ptgrp = (bid >> 5) & (PTGRPS - 1);
    const int batch = (bid >> 6) & (BATCH - 1);
    const int dir   = bid >> 8;

    const float* pts  = (dir == 0) ? pred : gt;
    const float* cand = (dir == 0) ? gt   : pred;

    // Stage this segment's 128 candidates (threads 0..127), computing -g2/2.
    if (threadIdx.x < CSEG) {
        const float* cb = cand + (size_t)batch * 3 * NPTS + seg * CSEG;
        const float x = cb[threadIdx.x];
        const float y = cb[NPTS + threadIdx.x];
        const float z = cb[2 * NPTS + threadIdx.x];
        const float s = -0.5f * fmaf(x, x, fmaf(y, y, z * z));
        lc[threadIdx.x] = make_float4(x, y, z, s);
    }
    __syncthreads();

    // This thread's 8 points (coalesced, stride-256 within the 2048-pt group).
    const float* pb = pts + (size_t)batch * 3 * NPTS;
    const int pbase = ptgrp * (THREADS * P) + threadIdx.x;
    float px[P], py[P], pz[P], smax[P];
    #pragma unroll
    for (int k = 0; k < P; ++k) {
        const int i = pbase + k * THREADS;
        px[k] = pb[i];
        py[k] = pb[NPTS + i];
        pz[k] = pb[2 * NPTS + i];
        smax[k] = -BIG;
    }

    // 32 groups of 4 candidates. Per group per wave: 4 ds_read_b128 (broadcast)
    // + 4*P*(3 fma + 1 max) VALU.
    #pragma unroll 2
    for (int g = 0; g < CSEG / 4; ++g) {
        const float4 c0 = lc[4 * g + 0];
        const float4 c1 = lc[4 * g + 1];
        const float4 c2 = lc[4 * g + 2];
        const float4 c3 = lc[4 * g + 3];
        #pragma unroll
        for (int k = 0; k < P; ++k) {
            float t0 = fmaf(px[k], c0.x, fmaf(py[k], c0.y, fmaf(pz[k], c0.z, c0.w)));
            float t1 = fmaf(px[k], c1.x, fmaf(py[k], c1.y, fmaf(pz[k], c1.z, c1.w)));
            float t2 = fmaf(px[k], c2.x, fmaf(py[k], c2.y, fmaf(pz[k], c2.z, c2.w)));
            float t3 = fmaf(px[k], c3.x, fmaf(py[k], c3.y, fmaf(pz[k], c3.z, c3.w)));
            smax[k] = fmaxf(smax[k], fmaxf(fmaxf(t0, t1), fmaxf(t2, t3)));
        }
    }

    // Convert back to d2 and store: pmin[seg][global_point], coalesced per k.
    const int gp = dir * (BATCH * NPTS) + batch * NPTS + pbase;
    #pragma unroll
    for (int k = 0; k < P; ++k) {
        const int i = pbase + k * THREADS;
        const float p2 = fmaf(px[k], px[k], fmaf(py[k], py[k], pz[k] * pz[k]));
        (void)i;
        pmin[(size_t)seg * TOTAL_PTS + gp + k * THREADS] = fmaf(-2.0f, smax[k], p2);
    }
}

// Pass 2: per point, min over the 32 segment d2s, clamp, sqrt(+eps), block-sum.
__global__ __launch_bounds__(THREADS) void chamfer_pass2(
    const float* __restrict__ pmin, float* __restrict__ bsum)
{
    const int pbase = blockIdx.x * (THREADS * P2) + threadIdx.x;
    float acc = 0.0f;
    #pragma unroll
    for (int k = 0; k < P2; ++k) {
        const int p = pbase + k * THREADS;
        float v = BIG;
        #pragma unroll
        for (int s = 0; s < SEGS; ++s)
            v = fminf(v, pmin[(size_t)s * TOTAL_PTS + p]);
        acc += sqrtf(fmaxf(v, 0.0f) + EPS);
    }
    #pragma unroll
    for (int off = 32; off; off >>= 1) acc += __shfl_down(acc, off, 64);
    __shared__ float wsum[THREADS / 64];
    if ((threadIdx.x & 63) == 0) wsum[threadIdx.x >> 6] = acc;
    __syncthreads();
    if (threadIdx.x == 0)
        bsum[blockIdx.x] = (wsum[0] + wsum[1]) + (wsum[2] + wsum[3]);
}

// Pass 3: reduce 32 block sums; both means share denominator B*NPTS = 16384.
__global__ void chamfer_pass3(const float* __restrict__ bsum, float* __restrict__ out)
{
    float v = (threadIdx.x < PASS2_BLOCKS) ? bsum[threadIdx.x] : 0.0f;
    #pragma unroll
    for (int off = 32; off; off >>= 1) v += __shfl_down(v, off, 64);
    if (threadIdx.x == 0)
        out[0] = v * (1.0f / (float)(BATCH * NPTS));
}

extern "C" void kernel_launch(void* const* d_in, const int* in_sizes, int n_in,
                              void* d_out, int out_size, void* d_ws, size_t ws_size,
                              hipStream_t stream) {
    const float* pred = (const float*)d_in[0];
    const float* gt   = (const float*)d_in[1];
    float* out  = (float*)d_out;
    float* pmin = (float*)d_ws;              // 4MB partial d2 mins (all slots written)
    float* bsum = pmin + PMIN_FLOATS;        // 32 block sums

    chamfer_pass1<<<PASS1_BLOCKS, THREADS, 0, stream>>>(pred, gt, pmin);
    chamfer_pass2<<<PASS2_BLOCKS, THREADS, 0, stream>>>(pmin, bsum);
    chamfer_pass3<<<1, 64, 0, stream>>>(bsum, out);
}